// Round 15
// baseline (93.828 us; speedup 1.0000x reference)
//
#include <hip/hip_runtime.h>
#include <hip/hip_bf16.h>
#include <math.h>

#define B_ 4096
#define F_ 64
#define A_ 8
#define U_ 32

typedef float f32x4 __attribute__((ext_vector_type(4)));
typedef short bf16x8 __attribute__((ext_vector_type(8)));

// ws layout:
//   [0, 4 MB): frag blob, per (a,j) 8192 B, index (a*64+j):
//     [0,4096):  K frags, fragid = kc*2+ut, 64 lanes x 16 B:
//                bf16( K[f = kc*32 + q*8 + i][u = ut*16 + c] * log2(e) ), with ROW j
//                ZEROED (exact exclusion mask — no runtime correction needed).
//                Z' = mfma(Kfrag, Xfrag) gives z*log2e; e^z = exp2(Z').
//     [4096,8192): W frags, fragid = ft, u-PERMUTED to the Z^T slot order:
//                slot i of lane (q,c): bf16 exp(2*K[f = ft*16 + c][u = pi(q,i)]),
//                pi(q,i) = (i<4) ? 4q+i : 16 + 4q + (i-4)   (W keeps ALL rows, incl. f=j)

static __device__ __forceinline__ unsigned int pk_bf16(float lo, float hi) {
    union { __hip_bfloat162 h2; unsigned int u; } cv;
    cv.h2 = __float22bfloat162_rn(make_float2(lo, hi));
    return cv.u;
}

// ---------------- prep: one block per (a,j); stage 8 KB, emit frags ----------------
__global__ __launch_bounds__(256) void ife_prep(const float* __restrict__ kern,
                                                unsigned char* __restrict__ ws)
{
    const int bid = blockIdx.x;           // a*64 + j
    const int a = bid >> 6, j = bid & 63;
    const int t = threadIdx.x;
    __shared__ float st[64][36];          // [f][u], pitch 36 (16B-aligned float4 slots)

    const float* src = kern + ((size_t)j * A_ + a) * (F_ * U_);
    {
        const int f = t >> 2, u0 = (t & 3) * 8;
        *(float4*)&st[f][u0]     = *(const float4*)&src[f * U_ + u0];
        *(float4*)&st[f][u0 + 4] = *(const float4*)&src[f * U_ + u0 + 4];
    }
    __syncthreads();

    unsigned char* dst = ws + (size_t)bid * 8192;
    const int fragid = t >> 6, lane = t & 63, q = lane >> 4, c = lane & 15;
    const float L2E = 1.44269504088896341f;

    // K frag (fragid = kc*2 + ut): scaled by log2e, row j zeroed
    {
        const int kc = fragid >> 1, ut = fragid & 1;
        const int f0 = kc * 32 + q * 8, u = ut * 16 + c;
        unsigned int w[4];
        #pragma unroll
        for (int i = 0; i < 4; ++i) {
            const int fA = f0 + 2 * i, fB = f0 + 2 * i + 1;
            const float vA = (fA == j) ? 0.f : st[fA][u] * L2E;
            const float vB = (fB == j) ? 0.f : st[fB][u] * L2E;
            w[i] = pk_bf16(vA, vB);
        }
        *(uint4*)(dst + fragid * 1024 + lane * 16) = make_uint4(w[0], w[1], w[2], w[3]);
    }
    // W frag (fragid = ft), u-permuted: slots = {4q..4q+3, 16+4q..16+4q+3}
    {
        const int f = fragid * 16 + c;
        const float4 wa = *(const float4*)&st[f][q * 4];        // u = 4q .. 4q+3
        const float4 wb = *(const float4*)&st[f][16 + q * 4];   // u = 16+4q .. 16+4q+3
        unsigned int w[4];
        w[0] = pk_bf16(__expf(2.f * wa.x), __expf(2.f * wa.y));
        w[1] = pk_bf16(__expf(2.f * wa.z), __expf(2.f * wa.w));
        w[2] = pk_bf16(__expf(2.f * wb.x), __expf(2.f * wb.y));
        w[3] = pk_bf16(__expf(2.f * wb.z), __expf(2.f * wb.w));
        *(uint4*)(dst + 4096 + fragid * 1024 + lane * 16) = make_uint4(w[0], w[1], w[2], w[3]);
    }
}

// ---------------- main: (a, 64-row tile); 8 waves = 4 j-groups x 2 row-halves ------------
// Combines the session's two verified wins, never before together:
//  - R13 geometry: 32 rows/wave (2 row-blocks), 16 steps — each staged tile read by 2
//    waves not 4 -> HALF the total ds_read_b128 traffic and half the barriers;
//  - R14 sync: vmcnt-only wait after compute + raw s_barrier (no lgkmcnt/expcnt drain).
// Per step: STAGE(s+1) at top (async, hides under compute), compute both row-blocks,
// s_waitcnt vmcnt(0) (loads had ~2000 cy to land vs ~200-500 cy L2/L3 latency),
// sched_barrier, raw s_barrier. Body = R12 minimal (mask+log2e folded, ONES denom, exp2).
__global__ __launch_bounds__(512, 4) void ife_main(const float* __restrict__ x,
                                                   const unsigned char* __restrict__ ws,
                                                   float* __restrict__ out)
{
    const int a = blockIdx.y, bt = blockIdx.x, t = threadIdx.x;
    const int wv = t >> 6, lane = t & 63, q = lane >> 4, c = lane & 15;
    const int jg = wv >> 1, rh = wv & 1;   // j-group (4), row-half (2)

    __shared__ __align__(16) unsigned char Fbuf[2][4][8192];  // frag dbuf, 4 tiles (64 KB)

    // X frags for both row-blocks of this wave's half (B operand of Z^T)
    bf16x8 Xh[2][2];
    #pragma unroll
    for (int rb_ = 0; rb_ < 2; ++rb_) {
        const float* xr = x + (size_t)(bt * 64 + rh * 32 + rb_ * 16 + c) * F_;
        #pragma unroll
        for (int kc = 0; kc < 2; ++kc) {
            const float4 va = *(const float4*)&xr[kc * 32 + q * 8];
            const float4 vb = *(const float4*)&xr[kc * 32 + q * 8 + 4];
            union { unsigned int u[4]; bf16x8 v; } H;
            H.u[0] = pk_bf16(va.x, va.y);
            H.u[1] = pk_bf16(va.z, va.w);
            H.u[2] = pk_bf16(vb.x, vb.y);
            H.u[3] = pk_bf16(vb.z, vb.w);
            Xh[rb_][kc] = H.v;
        }
    }

    const unsigned char* blob = ws + (size_t)a * 64 * 8192;
    const f32x4 vzero = (f32x4){0.f, 0.f, 0.f, 0.f};

    union { unsigned int u[4]; bf16x8 v; } oc;
    oc.u[0] = 0x3F803F80u; oc.u[1] = 0x3F803F80u; oc.u[2] = 0x3F803F80u; oc.u[3] = 0x3F803F80u;
    const bf16x8 ONES = oc.v;

    f32x4 S[2][4];   // [row-block][ft]: score[row][f = ft*16 + 4q + r]
    #pragma unroll
    for (int rb_ = 0; rb_ < 2; ++rb_) {
        S[rb_][0] = vzero; S[rb_][1] = vzero; S[rb_][2] = vzero; S[rb_][3] = vzero;
    }

    // stage step s: 4 tiles (j = tile*16 + s); wave wv covers tile wv>>1, half wv&1 (4 KB)
    typedef const __attribute__((address_space(1))) unsigned int gau32;
    typedef __attribute__((address_space(3))) unsigned int lau32;
    auto STAGE = [&](int buf, int s) {
        const int tile = wv >> 1, half = wv & 1;
        const int jt = tile * 16 + s;
        const unsigned char* g = blob + (size_t)jt * 8192 + half * 4096 + lane * 16;
        unsigned char* l = &Fbuf[buf][tile][half * 4096];
        __builtin_amdgcn_global_load_lds((gau32*)(g),        (lau32*)(l),        16, 0, 0);
        __builtin_amdgcn_global_load_lds((gau32*)(g + 1024), (lau32*)(l + 1024), 16, 0, 0);
        __builtin_amdgcn_global_load_lds((gau32*)(g + 2048), (lau32*)(l + 2048), 16, 0, 0);
        __builtin_amdgcn_global_load_lds((gau32*)(g + 3072), (lau32*)(l + 3072), 16, 0, 0);
    };

    // prologue: stage s=0, drain (X loads + staging), raw barrier
    STAGE(0, 0);
    asm volatile("s_waitcnt vmcnt(0)" ::: "memory");
    __builtin_amdgcn_sched_barrier(0);
    __builtin_amdgcn_s_barrier();
    __builtin_amdgcn_sched_barrier(0);

    int cur = 0;
    #pragma unroll 1
    for (int s = 0; s < 16; ++s) {
        if (s < 15) STAGE(cur ^ 1, s + 1);       // async; hides under this step's compute

        const unsigned char* pt = &Fbuf[cur][jg][lane * 16];

        // frag reads from LDS (ds_read_b128; lane-consecutive 16B = conflict-free)
        const bf16x8 K0 = *(const bf16x8*)(pt);
        const bf16x8 K1 = *(const bf16x8*)(pt + 1024);
        const bf16x8 K2 = *(const bf16x8*)(pt + 2048);
        const bf16x8 K3 = *(const bf16x8*)(pt + 3072);
        const bf16x8 W0 = *(const bf16x8*)(pt + 4096);
        const bf16x8 W1 = *(const bf16x8*)(pt + 5120);
        const bf16x8 W2 = *(const bf16x8*)(pt + 6144);
        const bf16x8 W3 = *(const bf16x8*)(pt + 7168);

        // Z' = (z*log2e)^T, exclusion pre-applied. Lane (q,c): ZA->u=4q+r, ZB->u=16+4q+r.
        f32x4 ZA0 = vzero, ZB0 = vzero, ZA1 = vzero, ZB1 = vzero;
        ZA0 = __builtin_amdgcn_mfma_f32_16x16x32_bf16(K0, Xh[0][0], ZA0, 0, 0, 0);
        ZA0 = __builtin_amdgcn_mfma_f32_16x16x32_bf16(K2, Xh[0][1], ZA0, 0, 0, 0);
        ZB0 = __builtin_amdgcn_mfma_f32_16x16x32_bf16(K1, Xh[0][0], ZB0, 0, 0, 0);
        ZB0 = __builtin_amdgcn_mfma_f32_16x16x32_bf16(K3, Xh[0][1], ZB0, 0, 0, 0);
        ZA1 = __builtin_amdgcn_mfma_f32_16x16x32_bf16(K0, Xh[1][0], ZA1, 0, 0, 0);
        ZA1 = __builtin_amdgcn_mfma_f32_16x16x32_bf16(K2, Xh[1][1], ZA1, 0, 0, 0);
        ZB1 = __builtin_amdgcn_mfma_f32_16x16x32_bf16(K1, Xh[1][0], ZB1, 0, 0, 0);
        ZB1 = __builtin_amdgcn_mfma_f32_16x16x32_bf16(K3, Xh[1][1], ZB1, 0, 0, 0);

        // row-block 0: e = 2^Z' (single v_exp each), pack, ONES-denominator, PV
        {
            union { unsigned int u[4]; bf16x8 v; } E;
            E.u[0] = pk_bf16(__builtin_amdgcn_exp2f(ZA0[0]), __builtin_amdgcn_exp2f(ZA0[1]));
            E.u[1] = pk_bf16(__builtin_amdgcn_exp2f(ZA0[2]), __builtin_amdgcn_exp2f(ZA0[3]));
            E.u[2] = pk_bf16(__builtin_amdgcn_exp2f(ZB0[0]), __builtin_amdgcn_exp2f(ZB0[1]));
            E.u[3] = pk_bf16(__builtin_amdgcn_exp2f(ZB0[2]), __builtin_amdgcn_exp2f(ZB0[3]));
            const f32x4 sv = __builtin_amdgcn_mfma_f32_16x16x32_bf16(ONES, E.v, vzero, 0, 0, 0);
            const f32x4 D0 = __builtin_amdgcn_mfma_f32_16x16x32_bf16(W0, E.v, vzero, 0, 0, 0);
            const f32x4 D1 = __builtin_amdgcn_mfma_f32_16x16x32_bf16(W1, E.v, vzero, 0, 0, 0);
            const f32x4 D2 = __builtin_amdgcn_mfma_f32_16x16x32_bf16(W2, E.v, vzero, 0, 0, 0);
            const f32x4 D3 = __builtin_amdgcn_mfma_f32_16x16x32_bf16(W3, E.v, vzero, 0, 0, 0);
            const float inv = __builtin_amdgcn_rcpf(sv[0]);
            #pragma unroll
            for (int r = 0; r < 4; ++r) {
                S[0][0][r] += D0[r] * inv;
                S[0][1][r] += D1[r] * inv;
                S[0][2][r] += D2[r] * inv;
                S[0][3][r] += D3[r] * inv;
            }
        }
        // row-block 1
        {
            union { unsigned int u[4]; bf16x8 v; } E;
            E.u[0] = pk_bf16(__builtin_amdgcn_exp2f(ZA1[0]), __builtin_amdgcn_exp2f(ZA1[1]));
            E.u[1] = pk_bf16(__builtin_amdgcn_exp2f(ZA1[2]), __builtin_amdgcn_exp2f(ZA1[3]));
            E.u[2] = pk_bf16(__builtin_amdgcn_exp2f(ZB1[0]), __builtin_amdgcn_exp2f(ZB1[1]));
            E.u[3] = pk_bf16(__builtin_amdgcn_exp2f(ZB1[2]), __builtin_amdgcn_exp2f(ZB1[3]));
            const f32x4 sv = __builtin_amdgcn_mfma_f32_16x16x32_bf16(ONES, E.v, vzero, 0, 0, 0);
            const f32x4 D0 = __builtin_amdgcn_mfma_f32_16x16x32_bf16(W0, E.v, vzero, 0, 0, 0);
            const f32x4 D1 = __builtin_amdgcn_mfma_f32_16x16x32_bf16(W1, E.v, vzero, 0, 0, 0);
            const f32x4 D2 = __builtin_amdgcn_mfma_f32_16x16x32_bf16(W2, E.v, vzero, 0, 0, 0);
            const f32x4 D3 = __builtin_amdgcn_mfma_f32_16x16x32_bf16(W3, E.v, vzero, 0, 0, 0);
            const float inv = __builtin_amdgcn_rcpf(sv[0]);
            #pragma unroll
            for (int r = 0; r < 4; ++r) {
                S[1][0][r] += D0[r] * inv;
                S[1][1][r] += D1[r] * inv;
                S[1][2][r] += D2[r] * inv;
                S[1][3][r] += D3[r] * inv;
            }
        }

        // counted sync: my s+1 staging loads complete (had the whole compute to land),
        // then raw barrier -> all halves of all tiles complete. No lgkm/exp drain.
        if (s < 15) {
            asm volatile("s_waitcnt vmcnt(0)" ::: "memory");
            __builtin_amdgcn_sched_barrier(0);
            __builtin_amdgcn_s_barrier();
            __builtin_amdgcn_sched_barrier(0);
        }
        cur ^= 1;
    }

    // ---- reduce partial S across the 4 j-groups through LDS (reuse Fbuf: 64 KB) ----
    __syncthreads();                            // all step-15 reads complete
    float* Sred = (float*)Fbuf;                 // [wave][lane][32 floats]
    {
        float* pp = Sred + ((size_t)wv * 64 + lane) * 32;
        #pragma unroll
        for (int rb_ = 0; rb_ < 2; ++rb_)
            #pragma unroll
            for (int ft = 0; ft < 4; ++ft)
                *(f32x4*)(pp + rb_ * 16 + ft * 4) = S[rb_][ft];
    }
    __syncthreads();
    if (jg == 0) {
        f32x4 F[2][4];
        #pragma unroll
        for (int rb_ = 0; rb_ < 2; ++rb_) {
            F[rb_][0] = vzero; F[rb_][1] = vzero; F[rb_][2] = vzero; F[rb_][3] = vzero;
        }
        #pragma unroll
        for (int g = 0; g < 4; ++g) {
            const float* pp = Sred + ((size_t)(g * 2 + rh) * 64 + lane) * 32;
            #pragma unroll
            for (int rb_ = 0; rb_ < 2; ++rb_)
                #pragma unroll
                for (int ft = 0; ft < 4; ++ft)
                    F[rb_][ft] += *(const f32x4*)(pp + rb_ * 16 + ft * 4);
        }

        // epilogue: mean over j, softmax over f (log2e folded into the scale).
        // Lane (q,c): row's f = ft*16 + 4q + r.
        const float sc2 = 1.44269504088896341f / 64.f;
        #pragma unroll
        for (int rb_ = 0; rb_ < 2; ++rb_) {
            float ex[4][4];
            float part = 0.f;
            #pragma unroll
            for (int r = 0; r < 4; ++r) {
                ex[0][r] = __builtin_amdgcn_exp2f(F[rb_][0][r] * sc2);
                ex[1][r] = __builtin_amdgcn_exp2f(F[rb_][1][r] * sc2);
                ex[2][r] = __builtin_amdgcn_exp2f(F[rb_][2][r] * sc2);
                ex[3][r] = __builtin_amdgcn_exp2f(F[rb_][3][r] * sc2);
                part += ex[0][r] + ex[1][r] + ex[2][r] + ex[3][r];
            }
            part += __shfl_xor(part, 16, 64);
            part += __shfl_xor(part, 32, 64);
            const float inv = 1.f / part;

            const int b = bt * 64 + rh * 32 + rb_ * 16 + c;
            float* o = out + ((size_t)a * B_ + b) * F_;
            #pragma unroll
            for (int ft = 0; ft < 4; ++ft) {
                float4 v;
                v.x = ex[ft][0] * inv;
                v.y = ex[ft][1] * inv;
                v.z = ex[ft][2] * inv;
                v.w = ex[ft][3] * inv;
                *(float4*)&o[ft * 16 + q * 4] = v;
            }
        }
    }
}

extern "C" void kernel_launch(void* const* d_in, const int* in_sizes, int n_in,
                              void* d_out, int out_size, void* d_ws, size_t ws_size,
                              hipStream_t stream) {
    (void)in_sizes; (void)n_in; (void)out_size; (void)ws_size;
    const float* x    = (const float*)d_in[0];   // [B, F]
    const float* kern = (const float*)d_in[1];   // [F, A, F, U]
    float* out        = (float*)d_out;           // [A, B, F]
    unsigned char* ws = (unsigned char*)d_ws;    // 4 MB used

    hipLaunchKernelGGL(ife_prep, dim3(F_ * A_), dim3(256), 0, stream, kern, ws);
    hipLaunchKernelGGL(ife_main, dim3(B_ / 64, A_), dim3(512), 0, stream, x, ws, out);
}

// Round 16
// 89.750 us; speedup vs baseline: 1.0454x; 1.0454x over previous
//
#include <hip/hip_runtime.h>
#include <hip/hip_bf16.h>
#include <math.h>

#define B_ 4096
#define F_ 64
#define A_ 8
#define U_ 32

typedef float f32x4 __attribute__((ext_vector_type(4)));
typedef short bf16x8 __attribute__((ext_vector_type(8)));

// ws layout:
//   [0, 4 MB): frag blob, per (a,j) 8192 B, index (a*64+j):
//     [0,4096):  K frags, fragid = kc*2+ut, 64 lanes x 16 B:
//                bf16( K[f = kc*32 + q*8 + i][u = ut*16 + c] * log2(e) ), with ROW j
//                ZEROED (exact exclusion mask — no runtime correction needed).
//                Z' = mfma(Kfrag, Xfrag) gives z*log2e; e^z = exp2(Z').
//     [4096,8192): W frags, fragid = ft, u-PERMUTED to the Z^T slot order:
//                slot i of lane (q,c): bf16 exp(2*K[f = ft*16 + c][u = pi(q,i)]),
//                pi(q,i) = (i<4) ? 4q+i : 16 + 4q + (i-4)   (W keeps ALL rows, incl. f=j)

static __device__ __forceinline__ unsigned int pk_bf16(float lo, float hi) {
    union { __hip_bfloat162 h2; unsigned int u; } cv;
    cv.h2 = __float22bfloat162_rn(make_float2(lo, hi));
    return cv.u;
}

// ---------------- prep: one block per (a,j); stage 8 KB, emit frags ----------------
__global__ __launch_bounds__(256) void ife_prep(const float* __restrict__ kern,
                                                unsigned char* __restrict__ ws)
{
    const int bid = blockIdx.x;           // a*64 + j
    const int a = bid >> 6, j = bid & 63;
    const int t = threadIdx.x;
    __shared__ float st[64][36];          // [f][u], pitch 36 (16B-aligned float4 slots)

    const float* src = kern + ((size_t)j * A_ + a) * (F_ * U_);
    {
        const int f = t >> 2, u0 = (t & 3) * 8;
        *(float4*)&st[f][u0]     = *(const float4*)&src[f * U_ + u0];
        *(float4*)&st[f][u0 + 4] = *(const float4*)&src[f * U_ + u0 + 4];
    }
    __syncthreads();

    unsigned char* dst = ws + (size_t)bid * 8192;
    const int fragid = t >> 6, lane = t & 63, q = lane >> 4, c = lane & 15;
    const float L2E = 1.44269504088896341f;

    // K frag (fragid = kc*2 + ut): scaled by log2e, row j zeroed
    {
        const int kc = fragid >> 1, ut = fragid & 1;
        const int f0 = kc * 32 + q * 8, u = ut * 16 + c;
        unsigned int w[4];
        #pragma unroll
        for (int i = 0; i < 4; ++i) {
            const int fA = f0 + 2 * i, fB = f0 + 2 * i + 1;
            const float vA = (fA == j) ? 0.f : st[fA][u] * L2E;
            const float vB = (fB == j) ? 0.f : st[fB][u] * L2E;
            w[i] = pk_bf16(vA, vB);
        }
        *(uint4*)(dst + fragid * 1024 + lane * 16) = make_uint4(w[0], w[1], w[2], w[3]);
    }
    // W frag (fragid = ft), u-permuted: slots = {4q..4q+3, 16+4q..16+4q+3}
    {
        const int f = fragid * 16 + c;
        const float4 wa = *(const float4*)&st[f][q * 4];        // u = 4q .. 4q+3
        const float4 wb = *(const float4*)&st[f][16 + q * 4];   // u = 16+4q .. 16+4q+3
        unsigned int w[4];
        w[0] = pk_bf16(__expf(2.f * wa.x), __expf(2.f * wa.y));
        w[1] = pk_bf16(__expf(2.f * wa.z), __expf(2.f * wa.w));
        w[2] = pk_bf16(__expf(2.f * wb.x), __expf(2.f * wb.y));
        w[3] = pk_bf16(__expf(2.f * wb.z), __expf(2.f * wb.w));
        *(uint4*)(dst + 4096 + fragid * 1024 + lane * 16) = make_uint4(w[0], w[1], w[2], w[3]);
    }
}

// ---------------- main: (a, 64-row tile); 8 waves = 2 j-groups x 4 row-waves --------------
// R14 champion (89.9 us) with ONE change: barrier frequency halved. 4-buffer ring (64 KB);
// each interval stages steps s+2,s+3 (4 loads/wave), computes s then s+1 (per-step frag
// reads keep register pressure at R14's level — the R15 mistake), then vmcnt(0) (own loads
// had 2 full steps to land => wait ~ free) + raw s_barrier. 16 barriers instead of 32.
// Body = R12 minimal (mask+log2e folded into blob, ONES denom, single-inst exp2).
__global__ __launch_bounds__(512, 4) void ife_main(const float* __restrict__ x,
                                                   const unsigned char* __restrict__ ws,
                                                   float* __restrict__ out)
{
    const int a = blockIdx.y, bt = blockIdx.x, t = threadIdx.x;
    const int wv = t >> 6, lane = t & 63, q = lane >> 4, c = lane & 15;
    const int grp = wv >> 2, w4 = wv & 3;   // j-group (2), row-wave (4 x 16 rows)

    __shared__ __align__(16) unsigned char Fbuf[4][2][8192];  // frag 4-ring (64 KB)

    // X frags (lane holds X[b-row = c][f = kc*32 + q*8 + i]) — B operand of Z^T
    bf16x8 Xh[2];
    {
        const float* xr = x + (size_t)(bt * 64 + w4 * 16 + c) * F_;
        #pragma unroll
        for (int kc = 0; kc < 2; ++kc) {
            const float4 va = *(const float4*)&xr[kc * 32 + q * 8];
            const float4 vb = *(const float4*)&xr[kc * 32 + q * 8 + 4];
            union { unsigned int u[4]; bf16x8 v; } H;
            H.u[0] = pk_bf16(va.x, va.y);
            H.u[1] = pk_bf16(va.z, va.w);
            H.u[2] = pk_bf16(vb.x, vb.y);
            H.u[3] = pk_bf16(vb.z, vb.w);
            Xh[kc] = H.v;
        }
    }

    const unsigned char* blob = ws + (size_t)a * 64 * 8192;
    const f32x4 vzero = (f32x4){0.f, 0.f, 0.f, 0.f};

    union { unsigned int u[4]; bf16x8 v; } oc;
    oc.u[0] = 0x3F803F80u; oc.u[1] = 0x3F803F80u; oc.u[2] = 0x3F803F80u; oc.u[3] = 0x3F803F80u;
    const bf16x8 ONES = oc.v;

    f32x4 S0 = vzero, S1 = vzero, S2 = vzero, S3 = vzero;   // S[ft]: score[row=c][f=ft*16+4q+r]

    // stage step s into Fbuf[buf]: both groups' tiles (j = g*32+s); wave wv covers
    // group wv>>2's tile, quarter wv&3 (2 KB via two 1 KB width-16 global_load_lds).
    typedef const __attribute__((address_space(1))) unsigned int gau32;
    typedef __attribute__((address_space(3))) unsigned int lau32;
    auto STAGE = [&](int buf, int s) {
        const int g = wv >> 2, fp = wv & 3;
        const unsigned char* gsrc = blob + (size_t)(g * 32 + s) * 8192 + fp * 2048 + lane * 16;
        unsigned char* l = &Fbuf[buf][g][fp * 2048];
        __builtin_amdgcn_global_load_lds((gau32*)(gsrc),        (lau32*)(l),        16, 0, 0);
        __builtin_amdgcn_global_load_lds((gau32*)(gsrc + 1024), (lau32*)(l + 1024), 16, 0, 0);
    };

    // one step's compute from buffer pointer pt (frags read per-step: R14 register level)
    auto COMPUTE = [&](const unsigned char* pt) {
        const bf16x8 K0 = *(const bf16x8*)(pt);
        const bf16x8 K1 = *(const bf16x8*)(pt + 1024);
        const bf16x8 K2 = *(const bf16x8*)(pt + 2048);
        const bf16x8 K3 = *(const bf16x8*)(pt + 3072);
        const bf16x8 W0 = *(const bf16x8*)(pt + 4096);
        const bf16x8 W1 = *(const bf16x8*)(pt + 5120);
        const bf16x8 W2 = *(const bf16x8*)(pt + 6144);
        const bf16x8 W3 = *(const bf16x8*)(pt + 7168);

        // Z' = (z*log2e)^T, exclusion pre-applied. Lane (q,c): ZA->u=4q+r, ZB->u=16+4q+r.
        f32x4 ZA = vzero, ZB = vzero;
        ZA = __builtin_amdgcn_mfma_f32_16x16x32_bf16(K0, Xh[0], ZA, 0, 0, 0);
        ZA = __builtin_amdgcn_mfma_f32_16x16x32_bf16(K2, Xh[1], ZA, 0, 0, 0);
        ZB = __builtin_amdgcn_mfma_f32_16x16x32_bf16(K1, Xh[0], ZB, 0, 0, 0);
        ZB = __builtin_amdgcn_mfma_f32_16x16x32_bf16(K3, Xh[1], ZB, 0, 0, 0);

        // e = 2^Z' (single v_exp each); pack to bf16 (E frag, u-permuted slot order)
        union { unsigned int u[4]; bf16x8 v; } E;
        E.u[0] = pk_bf16(__builtin_amdgcn_exp2f(ZA[0]), __builtin_amdgcn_exp2f(ZA[1]));
        E.u[1] = pk_bf16(__builtin_amdgcn_exp2f(ZA[2]), __builtin_amdgcn_exp2f(ZA[3]));
        E.u[2] = pk_bf16(__builtin_amdgcn_exp2f(ZB[0]), __builtin_amdgcn_exp2f(ZB[1]));
        E.u[3] = pk_bf16(__builtin_amdgcn_exp2f(ZB[2]), __builtin_amdgcn_exp2f(ZB[3]));

        // denominator via MFMA vs ONES A-frag (sums the bf16-ROUNDED values = what PV sums)
        const f32x4 sv = __builtin_amdgcn_mfma_f32_16x16x32_bf16(ONES, E.v, vzero, 0, 0, 0);

        // PV: D[ft] = W[ft] · E (u contraction; both sides share the same u-permutation)
        const f32x4 D0 = __builtin_amdgcn_mfma_f32_16x16x32_bf16(W0, E.v, vzero, 0, 0, 0);
        const f32x4 D1 = __builtin_amdgcn_mfma_f32_16x16x32_bf16(W1, E.v, vzero, 0, 0, 0);
        const f32x4 D2 = __builtin_amdgcn_mfma_f32_16x16x32_bf16(W2, E.v, vzero, 0, 0, 0);
        const f32x4 D3 = __builtin_amdgcn_mfma_f32_16x16x32_bf16(W3, E.v, vzero, 0, 0, 0);

        const float inv = __builtin_amdgcn_rcpf(sv[0]);
        #pragma unroll
        for (int r = 0; r < 4; ++r) {
            S0[r] += D0[r] * inv;
            S1[r] += D1[r] * inv;
            S2[r] += D2[r] * inv;
            S3[r] += D3[r] * inv;
        }
    };

    // prologue: stage s=0 and s=1, drain (X loads + staging), raw barrier
    STAGE(0, 0);
    STAGE(1, 1);
    asm volatile("s_waitcnt vmcnt(0)" ::: "memory");
    __builtin_amdgcn_sched_barrier(0);
    __builtin_amdgcn_s_barrier();
    __builtin_amdgcn_sched_barrier(0);

    #pragma unroll 1
    for (int k = 0; k < 16; ++k) {
        const int s = 2 * k;
        if (k < 15) {                            // stage the NEXT interval's two steps
            STAGE((s + 2) & 3, s + 2);
            STAGE((s + 3) & 3, s + 3);
        }

        COMPUTE(&Fbuf[s & 3][grp][lane * 16]);        // step s
        COMPUTE(&Fbuf[(s + 1) & 3][grp][lane * 16]);  // step s+1

        if (k < 15) {
            // own 4 staging loads had two full steps to land -> wait ~ free; then
            // raw barrier makes all waves' quarters visible. No lgkm/exp drain.
            asm volatile("s_waitcnt vmcnt(0)" ::: "memory");
            __builtin_amdgcn_sched_barrier(0);
            __builtin_amdgcn_s_barrier();
            __builtin_amdgcn_sched_barrier(0);
        }
    }

    // ---- combine the two j-groups' partial S through LDS (overlay on Fbuf) ----
    __syncthreads();                            // all step-31 reads complete
    float* Sred = (float*)Fbuf;                 // [w4*64+lane][20] — 20.5 KB of 64 KB
    if (grp == 1) {
        float* pp = Sred + (size_t)(w4 * 64 + lane) * 20;
        *(f32x4*)(pp + 0)  = S0;
        *(f32x4*)(pp + 4)  = S1;
        *(f32x4*)(pp + 8)  = S2;
        *(f32x4*)(pp + 12) = S3;
    }
    __syncthreads();
    if (grp == 0) {
        const float* pp = Sred + (size_t)(w4 * 64 + lane) * 20;
        S0 += *(const f32x4*)(pp + 0);
        S1 += *(const f32x4*)(pp + 4);
        S2 += *(const f32x4*)(pp + 8);
        S3 += *(const f32x4*)(pp + 12);

        // epilogue: mean over j, softmax over f (log2e folded into the scale).
        // Lane (q,c) holds row c's f = ft*16 + 4q + r.
        const float sc2 = 1.44269504088896341f / 64.f;
        float ex[4][4];
        float part = 0.f;
        #pragma unroll
        for (int r = 0; r < 4; ++r) {
            ex[0][r] = __builtin_amdgcn_exp2f(S0[r] * sc2);
            ex[1][r] = __builtin_amdgcn_exp2f(S1[r] * sc2);
            ex[2][r] = __builtin_amdgcn_exp2f(S2[r] * sc2);
            ex[3][r] = __builtin_amdgcn_exp2f(S3[r] * sc2);
            part += ex[0][r] + ex[1][r] + ex[2][r] + ex[3][r];
        }
        part += __shfl_xor(part, 16, 64);
        part += __shfl_xor(part, 32, 64);
        const float inv = 1.f / part;

        const int b = bt * 64 + w4 * 16 + c;
        float* o = out + ((size_t)a * B_ + b) * F_;
        #pragma unroll
        for (int ft = 0; ft < 4; ++ft) {
            float4 v;
            v.x = ex[ft][0] * inv;
            v.y = ex[ft][1] * inv;
            v.z = ex[ft][2] * inv;
            v.w = ex[ft][3] * inv;
            *(float4*)&o[ft * 16 + q * 4] = v;
        }
    }
}

extern "C" void kernel_launch(void* const* d_in, const int* in_sizes, int n_in,
                              void* d_out, int out_size, void* d_ws, size_t ws_size,
                              hipStream_t stream) {
    (void)in_sizes; (void)n_in; (void)out_size; (void)ws_size;
    const float* x    = (const float*)d_in[0];   // [B, F]
    const float* kern = (const float*)d_in[1];   // [F, A, F, U]
    float* out        = (float*)d_out;           // [A, B, F]
    unsigned char* ws = (unsigned char*)d_ws;    // 4 MB used

    hipLaunchKernelGGL(ife_prep, dim3(F_ * A_), dim3(256), 0, stream, kern, ws);
    hipLaunchKernelGGL(ife_main, dim3(B_ / 64, A_), dim3(512), 0, stream, x, ws, out);
}

// Round 17
// 89.180 us; speedup vs baseline: 1.0521x; 1.0064x over previous
//
#include <hip/hip_runtime.h>
#include <hip/hip_bf16.h>
#include <math.h>

#define B_ 4096
#define F_ 64
#define A_ 8
#define U_ 32

typedef float f32x4 __attribute__((ext_vector_type(4)));
typedef short bf16x8 __attribute__((ext_vector_type(8)));

// ws layout:
//   [0, 4 MB): frag blob, per (a,j) 8192 B, index (a*64+j):
//     [0,4096):  K frags, fragid = kc*2+ut, 64 lanes x 16 B:
//                bf16( K[f = kc*32 + q*8 + i][u = ut*16 + c] * log2(e) ), with ROW j
//                ZEROED (exact exclusion mask — no runtime correction needed).
//                Z' = mfma(Kfrag, Xfrag) gives z*log2e; e^z = exp2(Z').
//     [4096,8192): W frags, fragid = ft, u-PERMUTED to the Z^T slot order:
//                slot i of lane (q,c): bf16 exp(2*K[f = ft*16 + c][u = pi(q,i)]),
//                pi(q,i) = (i<4) ? 4q+i : 16 + 4q + (i-4)   (W keeps ALL rows, incl. f=j)

static __device__ __forceinline__ unsigned int pk_bf16(float lo, float hi) {
    union { __hip_bfloat162 h2; unsigned int u; } cv;
    cv.h2 = __float22bfloat162_rn(make_float2(lo, hi));
    return cv.u;
}

// ---------------- prep: one block per (a,j); stage 8 KB, emit frags ----------------
__global__ __launch_bounds__(256) void ife_prep(const float* __restrict__ kern,
                                                unsigned char* __restrict__ ws)
{
    const int bid = blockIdx.x;           // a*64 + j
    const int a = bid >> 6, j = bid & 63;
    const int t = threadIdx.x;
    __shared__ float st[64][36];          // [f][u], pitch 36 (16B-aligned float4 slots)

    const float* src = kern + ((size_t)j * A_ + a) * (F_ * U_);
    {
        const int f = t >> 2, u0 = (t & 3) * 8;
        *(float4*)&st[f][u0]     = *(const float4*)&src[f * U_ + u0];
        *(float4*)&st[f][u0 + 4] = *(const float4*)&src[f * U_ + u0 + 4];
    }
    __syncthreads();

    unsigned char* dst = ws + (size_t)bid * 8192;
    const int fragid = t >> 6, lane = t & 63, q = lane >> 4, c = lane & 15;
    const float L2E = 1.44269504088896341f;

    // K frag (fragid = kc*2 + ut): scaled by log2e, row j zeroed
    {
        const int kc = fragid >> 1, ut = fragid & 1;
        const int f0 = kc * 32 + q * 8, u = ut * 16 + c;
        unsigned int w[4];
        #pragma unroll
        for (int i = 0; i < 4; ++i) {
            const int fA = f0 + 2 * i, fB = f0 + 2 * i + 1;
            const float vA = (fA == j) ? 0.f : st[fA][u] * L2E;
            const float vB = (fB == j) ? 0.f : st[fB][u] * L2E;
            w[i] = pk_bf16(vA, vB);
        }
        *(uint4*)(dst + fragid * 1024 + lane * 16) = make_uint4(w[0], w[1], w[2], w[3]);
    }
    // W frag (fragid = ft), u-permuted: slots = {4q..4q+3, 16+4q..16+4q+3}
    {
        const int f = fragid * 16 + c;
        const float4 wa = *(const float4*)&st[f][q * 4];        // u = 4q .. 4q+3
        const float4 wb = *(const float4*)&st[f][16 + q * 4];   // u = 16+4q .. 16+4q+3
        unsigned int w[4];
        w[0] = pk_bf16(__expf(2.f * wa.x), __expf(2.f * wa.y));
        w[1] = pk_bf16(__expf(2.f * wa.z), __expf(2.f * wa.w));
        w[2] = pk_bf16(__expf(2.f * wb.x), __expf(2.f * wb.y));
        w[3] = pk_bf16(__expf(2.f * wb.z), __expf(2.f * wb.w));
        *(uint4*)(dst + 4096 + fragid * 1024 + lane * 16) = make_uint4(w[0], w[1], w[2], w[3]);
    }
}

// ---------------- main: (a, 64-row tile); 8 waves = 2 j-groups x 4 row-waves --------------
// R16 champion (89.7 us) + ONE change (T5): s_setprio(1) around the two pure-MFMA clusters.
// Mechanism: the 2 co-resident blocks/CU sit at independent phases of the counted-vmcnt
// schedule (one staging, one entering MFMA); priority steers CU issue slots to the
// MFMA-feeding waves (catalog T5: +21-39% on phase-split schedules, null on lockstep).
__global__ __launch_bounds__(512, 4) void ife_main(const float* __restrict__ x,
                                                   const unsigned char* __restrict__ ws,
                                                   float* __restrict__ out)
{
    const int a = blockIdx.y, bt = blockIdx.x, t = threadIdx.x;
    const int wv = t >> 6, lane = t & 63, q = lane >> 4, c = lane & 15;
    const int grp = wv >> 2, w4 = wv & 3;   // j-group (2), row-wave (4 x 16 rows)

    __shared__ __align__(16) unsigned char Fbuf[4][2][8192];  // frag 4-ring (64 KB)

    // X frags (lane holds X[b-row = c][f = kc*32 + q*8 + i]) — B operand of Z^T
    bf16x8 Xh[2];
    {
        const float* xr = x + (size_t)(bt * 64 + w4 * 16 + c) * F_;
        #pragma unroll
        for (int kc = 0; kc < 2; ++kc) {
            const float4 va = *(const float4*)&xr[kc * 32 + q * 8];
            const float4 vb = *(const float4*)&xr[kc * 32 + q * 8 + 4];
            union { unsigned int u[4]; bf16x8 v; } H;
            H.u[0] = pk_bf16(va.x, va.y);
            H.u[1] = pk_bf16(va.z, va.w);
            H.u[2] = pk_bf16(vb.x, vb.y);
            H.u[3] = pk_bf16(vb.z, vb.w);
            Xh[kc] = H.v;
        }
    }

    const unsigned char* blob = ws + (size_t)a * 64 * 8192;
    const f32x4 vzero = (f32x4){0.f, 0.f, 0.f, 0.f};

    union { unsigned int u[4]; bf16x8 v; } oc;
    oc.u[0] = 0x3F803F80u; oc.u[1] = 0x3F803F80u; oc.u[2] = 0x3F803F80u; oc.u[3] = 0x3F803F80u;
    const bf16x8 ONES = oc.v;

    f32x4 S0 = vzero, S1 = vzero, S2 = vzero, S3 = vzero;   // S[ft]: score[row=c][f=ft*16+4q+r]

    // stage step s into Fbuf[buf]: both groups' tiles (j = g*32+s); wave wv covers
    // group wv>>2's tile, quarter wv&3 (2 KB via two 1 KB width-16 global_load_lds).
    typedef const __attribute__((address_space(1))) unsigned int gau32;
    typedef __attribute__((address_space(3))) unsigned int lau32;
    auto STAGE = [&](int buf, int s) {
        const int g = wv >> 2, fp = wv & 3;
        const unsigned char* gsrc = blob + (size_t)(g * 32 + s) * 8192 + fp * 2048 + lane * 16;
        unsigned char* l = &Fbuf[buf][g][fp * 2048];
        __builtin_amdgcn_global_load_lds((gau32*)(gsrc),        (lau32*)(l),        16, 0, 0);
        __builtin_amdgcn_global_load_lds((gau32*)(gsrc + 1024), (lau32*)(l + 1024), 16, 0, 0);
    };

    // one step's compute from buffer pointer pt (frags read per-step)
    auto COMPUTE = [&](const unsigned char* pt) {
        const bf16x8 K0 = *(const bf16x8*)(pt);
        const bf16x8 K1 = *(const bf16x8*)(pt + 1024);
        const bf16x8 K2 = *(const bf16x8*)(pt + 2048);
        const bf16x8 K3 = *(const bf16x8*)(pt + 3072);
        const bf16x8 W0 = *(const bf16x8*)(pt + 4096);
        const bf16x8 W1 = *(const bf16x8*)(pt + 5120);
        const bf16x8 W2 = *(const bf16x8*)(pt + 6144);
        const bf16x8 W3 = *(const bf16x8*)(pt + 7168);

        // Z' = (z*log2e)^T, exclusion pre-applied. Lane (q,c): ZA->u=4q+r, ZB->u=16+4q+r.
        f32x4 ZA = vzero, ZB = vzero;
        __builtin_amdgcn_s_setprio(1);                 // T5: favor the MFMA cluster
        ZA = __builtin_amdgcn_mfma_f32_16x16x32_bf16(K0, Xh[0], ZA, 0, 0, 0);
        ZA = __builtin_amdgcn_mfma_f32_16x16x32_bf16(K2, Xh[1], ZA, 0, 0, 0);
        ZB = __builtin_amdgcn_mfma_f32_16x16x32_bf16(K1, Xh[0], ZB, 0, 0, 0);
        ZB = __builtin_amdgcn_mfma_f32_16x16x32_bf16(K3, Xh[1], ZB, 0, 0, 0);
        __builtin_amdgcn_s_setprio(0);

        // e = 2^Z' (single v_exp each); pack to bf16 (E frag, u-permuted slot order)
        union { unsigned int u[4]; bf16x8 v; } E;
        E.u[0] = pk_bf16(__builtin_amdgcn_exp2f(ZA[0]), __builtin_amdgcn_exp2f(ZA[1]));
        E.u[1] = pk_bf16(__builtin_amdgcn_exp2f(ZA[2]), __builtin_amdgcn_exp2f(ZA[3]));
        E.u[2] = pk_bf16(__builtin_amdgcn_exp2f(ZB[0]), __builtin_amdgcn_exp2f(ZB[1]));
        E.u[3] = pk_bf16(__builtin_amdgcn_exp2f(ZB[2]), __builtin_amdgcn_exp2f(ZB[3]));

        // denominator + PV cluster (5 MFMAs), also priority-wrapped
        __builtin_amdgcn_s_setprio(1);
        const f32x4 sv = __builtin_amdgcn_mfma_f32_16x16x32_bf16(ONES, E.v, vzero, 0, 0, 0);
        const f32x4 D0 = __builtin_amdgcn_mfma_f32_16x16x32_bf16(W0, E.v, vzero, 0, 0, 0);
        const f32x4 D1 = __builtin_amdgcn_mfma_f32_16x16x32_bf16(W1, E.v, vzero, 0, 0, 0);
        const f32x4 D2 = __builtin_amdgcn_mfma_f32_16x16x32_bf16(W2, E.v, vzero, 0, 0, 0);
        const f32x4 D3 = __builtin_amdgcn_mfma_f32_16x16x32_bf16(W3, E.v, vzero, 0, 0, 0);
        __builtin_amdgcn_s_setprio(0);

        const float inv = __builtin_amdgcn_rcpf(sv[0]);
        #pragma unroll
        for (int r = 0; r < 4; ++r) {
            S0[r] += D0[r] * inv;
            S1[r] += D1[r] * inv;
            S2[r] += D2[r] * inv;
            S3[r] += D3[r] * inv;
        }
    };

    // prologue: stage s=0 and s=1, drain (X loads + staging), raw barrier
    STAGE(0, 0);
    STAGE(1, 1);
    asm volatile("s_waitcnt vmcnt(0)" ::: "memory");
    __builtin_amdgcn_sched_barrier(0);
    __builtin_amdgcn_s_barrier();
    __builtin_amdgcn_sched_barrier(0);

    #pragma unroll 1
    for (int k = 0; k < 16; ++k) {
        const int s = 2 * k;
        if (k < 15) {                            // stage the NEXT interval's two steps
            STAGE((s + 2) & 3, s + 2);
            STAGE((s + 3) & 3, s + 3);
        }

        COMPUTE(&Fbuf[s & 3][grp][lane * 16]);        // step s
        COMPUTE(&Fbuf[(s + 1) & 3][grp][lane * 16]);  // step s+1

        if (k < 15) {
            // own 4 staging loads had two full steps to land -> wait ~ free; then
            // raw barrier makes all waves' quarters visible. No lgkm/exp drain.
            asm volatile("s_waitcnt vmcnt(0)" ::: "memory");
            __builtin_amdgcn_sched_barrier(0);
            __builtin_amdgcn_s_barrier();
            __builtin_amdgcn_sched_barrier(0);
        }
    }

    // ---- combine the two j-groups' partial S through LDS (overlay on Fbuf) ----
    __syncthreads();                            // all step-31 reads complete
    float* Sred = (float*)Fbuf;                 // [w4*64+lane][20] — 20.5 KB of 64 KB
    if (grp == 1) {
        float* pp = Sred + (size_t)(w4 * 64 + lane) * 20;
        *(f32x4*)(pp + 0)  = S0;
        *(f32x4*)(pp + 4)  = S1;
        *(f32x4*)(pp + 8)  = S2;
        *(f32x4*)(pp + 12) = S3;
    }
    __syncthreads();
    if (grp == 0) {
        const float* pp = Sred + (size_t)(w4 * 64 + lane) * 20;
        S0 += *(const f32x4*)(pp + 0);
        S1 += *(const f32x4*)(pp + 4);
        S2 += *(const f32x4*)(pp + 8);
        S3 += *(const f32x4*)(pp + 12);

        // epilogue: mean over j, softmax over f (log2e folded into the scale).
        // Lane (q,c) holds row c's f = ft*16 + 4q + r.
        const float sc2 = 1.44269504088896341f / 64.f;
        float ex[4][4];
        float part = 0.f;
        #pragma unroll
        for (int r = 0; r < 4; ++r) {
            ex[0][r] = __builtin_amdgcn_exp2f(S0[r] * sc2);
            ex[1][r] = __builtin_amdgcn_exp2f(S1[r] * sc2);
            ex[2][r] = __builtin_amdgcn_exp2f(S2[r] * sc2);
            ex[3][r] = __builtin_amdgcn_exp2f(S3[r] * sc2);
            part += ex[0][r] + ex[1][r] + ex[2][r] + ex[3][r];
        }
        part += __shfl_xor(part, 16, 64);
        part += __shfl_xor(part, 32, 64);
        const float inv = 1.f / part;

        const int b = bt * 64 + w4 * 16 + c;
        float* o = out + ((size_t)a * B_ + b) * F_;
        #pragma unroll
        for (int ft = 0; ft < 4; ++ft) {
            float4 v;
            v.x = ex[ft][0] * inv;
            v.y = ex[ft][1] * inv;
            v.z = ex[ft][2] * inv;
            v.w = ex[ft][3] * inv;
            *(float4*)&o[ft * 16 + q * 4] = v;
        }
    }
}

extern "C" void kernel_launch(void* const* d_in, const int* in_sizes, int n_in,
                              void* d_out, int out_size, void* d_ws, size_t ws_size,
                              hipStream_t stream) {
    (void)in_sizes; (void)n_in; (void)out_size; (void)ws_size;
    const float* x    = (const float*)d_in[0];   // [B, F]
    const float* kern = (const float*)d_in[1];   // [F, A, F, U]
    float* out        = (float*)d_out;           // [A, B, F]
    unsigned char* ws = (unsigned char*)d_ws;    // 4 MB used

    hipLaunchKernelGGL(ife_prep, dim3(F_ * A_), dim3(256), 0, stream, kern, ws);
    hipLaunchKernelGGL(ife_main, dim3(B_ / 64, A_), dim3(512), 0, stream, x, ws, out);
}